// Round 1
// baseline (450.487 us; speedup 1.0000x reference)
//
#include <hip/hip_runtime.h>
#include <cstdint>
#include <cstddef>

typedef __bf16 bf16_t;
typedef __bf16 bf16x4 __attribute__((ext_vector_type(4)));
typedef __bf16 bf16x8 __attribute__((ext_vector_type(8)));
typedef float floatx4 __attribute__((ext_vector_type(4)));

#define NBATCH 2
#define NL     2048
#define NTOK   4096        // NBATCH*NL
#define DMODEL 1024
#define DINNER 2048
#define DSTATE 16
#define DTRANK 64
#define XPN    96          // DT_RANK + 2*D_STATE
#define NCHUNK 64
#define CS     32          // NL / NCHUNK

typedef const __attribute__((address_space(1))) void gvoid_t;
typedef __attribute__((address_space(3))) void lds_void_t;

__device__ __forceinline__ void gload_lds16(const bf16_t* g, bf16_t* l) {
  __builtin_amdgcn_global_load_lds((gvoid_t*)g, (lds_void_t*)l, 16, 0, 0);
}

// ---------------- elementwise converts ----------------
__global__ __launch_bounds__(256) void cvt_bf16(const float* __restrict__ src,
                                                bf16_t* __restrict__ dst, int n4) {
  int i = blockIdx.x * 256 + threadIdx.x;
  if (i >= n4) return;
  float4 v = ((const float4*)src)[i];
  bf16x4 o = { (bf16_t)v.x, (bf16_t)v.y, (bf16_t)v.z, (bf16_t)v.w };
  ((bf16x4*)dst)[i] = o;
}

// extract dt_low (cols 0..63 of x_dbl, row stride 96) -> bf16 (M x 64)
__global__ __launch_bounds__(256) void cvt_dtlow(const float* __restrict__ xdbl,
                                                 bf16_t* __restrict__ dst) {
  int i = blockIdx.x * 256 + threadIdx.x;   // 65536 float4 units
  int row = i >> 4, c4 = i & 15;
  float4 v = *(const float4*)(xdbl + (size_t)row * XPN + c4 * 4);
  bf16x4 o = { (bf16_t)v.x, (bf16_t)v.y, (bf16_t)v.z, (bf16_t)v.w };
  ((bf16x4*)dst)[i] = o;
}

// ---------------- fused add + rmsnorm -> bf16 ----------------
__global__ __launch_bounds__(256) void rmsnorm_kernel(const float* __restrict__ hid,
                                                      const float* __restrict__ res,
                                                      const float* __restrict__ w,
                                                      bf16_t* __restrict__ out) {
  int tok = blockIdx.x, tid = threadIdx.x;
  float4 a = ((const float4*)(hid + (size_t)tok * DMODEL))[tid];
  float4 b = ((const float4*)(res + (size_t)tok * DMODEL))[tid];
  float4 v = { a.x + b.x, a.y + b.y, a.z + b.z, a.w + b.w };
  float ss = v.x*v.x + v.y*v.y + v.z*v.z + v.w*v.w;
  #pragma unroll
  for (int o = 32; o > 0; o >>= 1) ss += __shfl_xor(ss, o);
  __shared__ float sred[4];
  if ((tid & 63) == 0) sred[tid >> 6] = ss;
  __syncthreads();
  float tot = sred[0] + sred[1] + sred[2] + sred[3];
  float scale = rsqrtf(tot * (1.0f / DMODEL) + 1e-5f);
  float4 wv = ((const float4*)w)[tid];
  bf16x4 o = { (bf16_t)(v.x*scale*wv.x), (bf16_t)(v.y*scale*wv.y),
               (bf16_t)(v.z*scale*wv.z), (bf16_t)(v.w*scale*wv.w) };
  ((bf16x4*)out)[(size_t)tok * (DMODEL/4) + tid] = o;
}

// ---------------- generic 128x128 GEMM, C = A * B^T (both K-major bf16) ------
// grid = (M/128)*NBn blocks of 256 threads; bm = bx / NBn, bn = bx % NBn
template <typename OutT>
__global__ __launch_bounds__(256) void gemm_bt_128(const bf16_t* __restrict__ A,
                                                   const bf16_t* __restrict__ B,
                                                   OutT* __restrict__ C,
                                                   int N, int K, int NBn) {
  __shared__ __align__(16) bf16_t sA[128 * 32];
  __shared__ __align__(16) bf16_t sB[128 * 32];
  int bx = blockIdx.x;
  int bm = bx / NBn, bn = bx % NBn;
  int tid = threadIdx.x;
  int lane = tid & 63, wave = tid >> 6;
  const bf16_t* Ab = A + (size_t)bm * 128 * K;
  const bf16_t* Bb = B + (size_t)bn * 128 * K;
  int c0 = wave * 64 + lane, c1 = c0 + 256;       // 512 16B-chunks per tile
  int r0 = c0 >> 2, k0c = (c0 & 3) * 8;
  int r1 = c1 >> 2, k1c = (c1 & 3) * 8;
  bf16_t* lA0 = sA + (size_t)(wave * 64) * 8;      // wave-uniform LDS bases
  bf16_t* lA1 = sA + (size_t)(256 + wave * 64) * 8;
  bf16_t* lB0 = sB + (size_t)(wave * 64) * 8;
  bf16_t* lB1 = sB + (size_t)(256 + wave * 64) * 8;

  floatx4 acc[4][4] = {};
  int wm = (wave & 1) * 64, wn = (wave >> 1) * 64;
  int lm = lane & 15, kq = (lane >> 4) * 8;

  for (int kk = 0; kk < K; kk += 32) {
    gload_lds16(Ab + (size_t)r0 * K + kk + k0c, lA0);
    gload_lds16(Ab + (size_t)r1 * K + kk + k1c, lA1);
    gload_lds16(Bb + (size_t)r0 * K + kk + k0c, lB0);
    gload_lds16(Bb + (size_t)r1 * K + kk + k1c, lB1);
    __syncthreads();
    bf16x8 a[4], b[4];
    #pragma unroll
    for (int i = 0; i < 4; i++) a[i] = *(const bf16x8*)&sA[(wm + i*16 + lm)*32 + kq];
    #pragma unroll
    for (int j = 0; j < 4; j++) b[j] = *(const bf16x8*)&sB[(wn + j*16 + lm)*32 + kq];
    #pragma unroll
    for (int i = 0; i < 4; i++)
      #pragma unroll
      for (int j = 0; j < 4; j++)
        acc[i][j] = __builtin_amdgcn_mfma_f32_16x16x32_bf16(a[i], b[j], acc[i][j], 0, 0, 0);
    __syncthreads();
  }
  int row0 = bm * 128 + wm + (lane >> 4) * 4;
  int col0 = bn * 128 + wn + lm;
  #pragma unroll
  for (int i = 0; i < 4; i++)
    #pragma unroll
    for (int j = 0; j < 4; j++)
      #pragma unroll
      for (int r = 0; r < 4; r++)
        C[(size_t)(row0 + i*16 + r) * N + col0 + j*16] = (OutT)acc[i][j][r];
}

// ---------------- causal depthwise conv(4) + SiLU ----------------
__global__ __launch_bounds__(256) void conv_silu(const bf16_t* __restrict__ xz,
                                                 const float* __restrict__ w,
                                                 const float* __restrict__ bias,
                                                 bf16_t* __restrict__ xc) {
  int idx = blockIdx.x * 256 + threadIdx.x;   // over NTOK*DINNER
  int e = idx & (DINNER - 1);
  int tok = idx >> 11;
  int l = tok & (NL - 1);
  float4 we = ((const float4*)w)[e];
  float acc = bias[e];
  float wk[4] = { we.x, we.y, we.z, we.w };
  #pragma unroll
  for (int k = 0; k < 4; k++) {
    int t = l - 3 + k;
    if (t >= 0) acc += (float)xz[(size_t)(tok - 3 + k) * (2*DINNER) + e] * wk[k];
  }
  float s = acc / (1.0f + __expf(-acc));
  xc[idx] = (bf16_t)s;
}

// ---------------- x_proj GEMM: (M x 2048) * (96 x 2048)^T, split-K=8, atomic --
__global__ __launch_bounds__(256) void gemm_xproj(const bf16_t* __restrict__ A,
                                                  const bf16_t* __restrict__ B,
                                                  float* __restrict__ C) {
  __shared__ __align__(16) bf16_t sA[128 * 32];
  __shared__ __align__(16) bf16_t sB[96 * 32];
  int bx = blockIdx.x;                 // 256: bm in [0,32), ks in [0,8)
  int bm = bx >> 3, ks = bx & 7;
  int tid = threadIdx.x, lane = tid & 63, wave = tid >> 6;
  const int K = DINNER;
  const bf16_t* Ab = A + (size_t)bm * 128 * K;
  int c0 = tid, c1 = tid + 256;
  int kbeg = ks * 256, kend = kbeg + 256;
  floatx4 acc[2][6] = {};
  int wrow = wave * 32;
  int lm = lane & 15, kq = (lane >> 4) * 8;
  for (int kk = kbeg; kk < kend; kk += 32) {
    gload_lds16(Ab + (size_t)(c0 >> 2) * K + kk + (c0 & 3) * 8, sA + (size_t)(wave*64)*8);
    gload_lds16(Ab + (size_t)(c1 >> 2) * K + kk + (c1 & 3) * 8, sA + (size_t)(256 + wave*64)*8);
    gload_lds16(B  + (size_t)(c0 >> 2) * K + kk + (c0 & 3) * 8, sB + (size_t)(wave*64)*8);
    if (wave < 2) {
      int c = 256 + wave * 64 + lane;
      gload_lds16(B + (size_t)(c >> 2) * K + kk + (c & 3) * 8, sB + (size_t)(256 + wave*64)*8);
    }
    __syncthreads();
    bf16x8 a[2], b[6];
    #pragma unroll
    for (int i = 0; i < 2; i++) a[i] = *(const bf16x8*)&sA[(wrow + i*16 + lm)*32 + kq];
    #pragma unroll
    for (int j = 0; j < 6; j++) b[j] = *(const bf16x8*)&sB[(j*16 + lm)*32 + kq];
    #pragma unroll
    for (int i = 0; i < 2; i++)
      #pragma unroll
      for (int j = 0; j < 6; j++)
        acc[i][j] = __builtin_amdgcn_mfma_f32_16x16x32_bf16(a[i], b[j], acc[i][j], 0, 0, 0);
    __syncthreads();
  }
  int row0 = bm * 128 + wrow + (lane >> 4) * 4;
  #pragma unroll
  for (int i = 0; i < 2; i++)
    #pragma unroll
    for (int j = 0; j < 6; j++)
      #pragma unroll
      for (int r = 0; r < 4; r++)
        atomicAdd(&C[(size_t)(row0 + i*16 + r) * XPN + j*16 + lm], acc[i][j][r]);
}

// ---------------- dt_proj GEMM (K=64) + bias + softplus -> bf16 ----------------
__global__ __launch_bounds__(256) void gemm_dtproj(const bf16_t* __restrict__ A,
                                                   const bf16_t* __restrict__ B,
                                                   const float* __restrict__ bias,
                                                   bf16_t* __restrict__ dt) {
  __shared__ __align__(16) bf16_t sA[128 * 64];
  __shared__ __align__(16) bf16_t sB[128 * 64];
  int bx = blockIdx.x;                 // 512: bm in [0,32), bn in [0,16)
  int bm = bx >> 4, bn = bx & 15;
  int tid = threadIdx.x, lane = tid & 63, wave = tid >> 6;
  #pragma unroll
  for (int rr = 0; rr < 4; rr++) {
    int c = rr * 256 + tid;
    int row = c >> 3, col = (c & 7) * 8;
    gload_lds16(A + (size_t)(bm * 128 + row) * 64 + col, sA + (size_t)(rr*256 + wave*64)*8);
    gload_lds16(B + (size_t)(bn * 128 + row) * 64 + col, sB + (size_t)(rr*256 + wave*64)*8);
  }
  __syncthreads();
  int wm = (wave & 1) * 64, wn = (wave >> 1) * 64;
  int lm = lane & 15, kq = (lane >> 4) * 8;
  floatx4 acc[4][4] = {};
  #pragma unroll
  for (int s = 0; s < 2; s++) {
    bf16x8 a[4], b[4];
    #pragma unroll
    for (int i = 0; i < 4; i++) a[i] = *(const bf16x8*)&sA[(wm + i*16 + lm)*64 + s*32 + kq];
    #pragma unroll
    for (int j = 0; j < 4; j++) b[j] = *(const bf16x8*)&sB[(wn + j*16 + lm)*64 + s*32 + kq];
    #pragma unroll
    for (int i = 0; i < 4; i++)
      #pragma unroll
      for (int j = 0; j < 4; j++)
        acc[i][j] = __builtin_amdgcn_mfma_f32_16x16x32_bf16(a[i], b[j], acc[i][j], 0, 0, 0);
  }
  int row0 = bm * 128 + wm + (lane >> 4) * 4;
  int col0 = bn * 128 + wn + lm;
  #pragma unroll
  for (int i = 0; i < 4; i++)
    #pragma unroll
    for (int j = 0; j < 4; j++) {
      float bv = bias[col0 + j*16];
      #pragma unroll
      for (int r = 0; r < 4; r++) {
        float v = acc[i][j][r] + bv;
        float sp = (v > 15.f) ? v : log1pf(__expf(v));
        dt[(size_t)(row0 + i*16 + r) * DINNER + col0 + j*16] = (bf16_t)sp;
      }
    }
}

// ---------------- scan pass A: per-chunk (sum_dt, h_end | h0=0) ----------------
__global__ __launch_bounds__(256) void scan_passA(const bf16_t* __restrict__ dt,
                                                  const bf16_t* __restrict__ x,
                                                  const float* __restrict__ xdbl,
                                                  const float* __restrict__ A_log,
                                                  float* __restrict__ qbuf,
                                                  float* __restrict__ sdbuf) {
  int bx = blockIdx.x;                  // 1024 = b(2) * chunk(64) * dgrp(8)
  int dgrp = bx & 7, chunk = (bx >> 3) & 63, bb = bx >> 9;
  int tid = threadIdx.x;
  int d = dgrp * 256 + tid;
  int t0 = chunk * CS;
  __shared__ float sBC[CS * 32];
  {
    int i = tid * 4;
    int t = i >> 5, c = i & 31;
    float4 v = *(const float4*)(xdbl + (size_t)(bb * NL + t0 + t) * XPN + DTRANK + c);
    *(float4*)(sBC + t * 32 + c) = v;
  }
  float a2[DSTATE];
  {
    const float4* Ar = (const float4*)(A_log + (size_t)d * DSTATE);
    #pragma unroll
    for (int q = 0; q < 4; q++) {
      float4 v = Ar[q];
      a2[q*4+0] = -__expf(v.x) * 1.44269504f;
      a2[q*4+1] = -__expf(v.y) * 1.44269504f;
      a2[q*4+2] = -__expf(v.z) * 1.44269504f;
      a2[q*4+3] = -__expf(v.w) * 1.44269504f;
    }
  }
  __syncthreads();
  float h[DSTATE];
  #pragma unroll
  for (int n = 0; n < DSTATE; n++) h[n] = 0.f;
  float sum_dt = 0.f;
  size_t base = (size_t)(bb * NL + t0) * DINNER + d;
  for (int t = 0; t < CS; t++) {
    float dtv = (float)dt[base + (size_t)t * DINNER];
    float xv  = (float)x [base + (size_t)t * DINNER];
    float dtx = dtv * xv;
    sum_dt += dtv;
    const float* Bt = sBC + t * 32;
    #pragma unroll
    for (int n = 0; n < DSTATE; n++) {
      float da = exp2f(dtv * a2[n]);
      h[n] = da * h[n] + dtx * Bt[n];
    }
  }
  size_t qb = ((size_t)((bb * NCHUNK + chunk) * DINNER + d)) * DSTATE;
  #pragma unroll
  for (int q = 0; q < 4; q++) {
    float4 v = { h[q*4], h[q*4+1], h[q*4+2], h[q*4+3] };
    *(float4*)(qbuf + qb + q*4) = v;
  }
  sdbuf[(size_t)(bb * NCHUNK + chunk) * DINNER + d] = sum_dt;
}

// ---------------- scan pass B: inter-chunk scan; qbuf <- h_start per chunk -----
__global__ __launch_bounds__(256) void scan_passB(const float* __restrict__ A_log,
                                                  const float* __restrict__ sdbuf,
                                                  float* __restrict__ qbuf) {
  int idx = blockIdx.x * 256 + threadIdx.x;   // 65536 = b*DINNER*DSTATE
  int n = idx & 15, dd = (idx >> 4) & (DINNER - 1), bb = idx >> 15;
  float a2 = -__expf(A_log[(size_t)dd * DSTATE + n]) * 1.44269504f;
  float h = 0.f;
  for (int c = 0; c < NCHUNK; c++) {
    size_t q = ((size_t)((bb * NCHUNK + c) * DINNER + dd)) * DSTATE + n;
    float Q = qbuf[q];
    float P = exp2f(a2 * sdbuf[(size_t)(bb * NCHUNK + c) * DINNER + dd]);
    qbuf[q] = h;
    h = P * h + Q;
  }
}

// ---------------- scan pass C: replay from h_start, fused y/gate -> bf16 -------
__global__ __launch_bounds__(256) void scan_passC(const bf16_t* __restrict__ dt,
                                                  const bf16_t* __restrict__ x,
                                                  const bf16_t* __restrict__ xz,
                                                  const float* __restrict__ xdbl,
                                                  const float* __restrict__ A_log,
                                                  const float* __restrict__ Dp,
                                                  const float* __restrict__ qbuf,
                                                  bf16_t* __restrict__ y) {
  int bx = blockIdx.x;
  int dgrp = bx & 7, chunk = (bx >> 3) & 63, bb = bx >> 9;
  int tid = threadIdx.x;
  int d = dgrp * 256 + tid;
  int t0 = chunk * CS;
  __shared__ float sBC[CS * 32];
  {
    int i = tid * 4;
    int t = i >> 5, c = i & 31;
    float4 v = *(const float4*)(xdbl + (size_t)(bb * NL + t0 + t) * XPN + DTRANK + c);
    *(float4*)(sBC + t * 32 + c) = v;
  }
  float a2[DSTATE];
  {
    const float4* Ar = (const float4*)(A_log + (size_t)d * DSTATE);
    #pragma unroll
    for (int q = 0; q < 4; q++) {
      float4 v = Ar[q];
      a2[q*4+0] = -__expf(v.x) * 1.44269504f;
      a2[q*4+1] = -__expf(v.y) * 1.44269504f;
      a2[q*4+2] = -__expf(v.z) * 1.44269504f;
      a2[q*4+3] = -__expf(v.w) * 1.44269504f;
    }
  }
  float h[DSTATE];
  {
    size_t qb = ((size_t)((bb * NCHUNK + chunk) * DINNER + d)) * DSTATE;
    #pragma unroll
    for (int q = 0; q < 4; q++) {
      float4 v = *(const float4*)(qbuf + qb + q*4);
      h[q*4] = v.x; h[q*4+1] = v.y; h[q*4+2] = v.z; h[q*4+3] = v.w;
    }
  }
  float Dv = Dp[d];
  __syncthreads();
  size_t base = (size_t)(bb * NL + t0) * DINNER + d;
  size_t zbase = (size_t)(bb * NL + t0) * (2*DINNER) + DINNER + d;
  for (int t = 0; t < CS; t++) {
    float dtv = (float)dt[base + (size_t)t * DINNER];
    float xv  = (float)x [base + (size_t)t * DINNER];
    float dtx = dtv * xv;
    const float* Bt = sBC + t * 32;
    const float* Ct = Bt + DSTATE;
    float yv = 0.f;
    #pragma unroll
    for (int n = 0; n < DSTATE; n++) {
      float da = exp2f(dtv * a2[n]);
      h[n] = da * h[n] + dtx * Bt[n];
      yv += h[n] * Ct[n];
    }
    yv += Dv * xv;
    float zv = (float)xz[zbase + (size_t)t * (2*DINNER)];
    yv *= zv / (1.0f + __expf(-zv));
    y[base + (size_t)t * DINNER] = (bf16_t)yv;
  }
}

// ---------------- host launcher ----------------
extern "C" void kernel_launch(void* const* d_in, const int* in_sizes, int n_in,
                              void* d_out, int out_size, void* d_ws, size_t ws_size,
                              hipStream_t stream) {
  const float* hidden   = (const float*)d_in[1];
  const float* residual = (const float*)d_in[2];
  const float* norm_w   = (const float*)d_in[3];
  const float* in_proj  = (const float*)d_in[4];
  const float* conv_w   = (const float*)d_in[5];
  const float* conv_b   = (const float*)d_in[6];
  const float* x_proj   = (const float*)d_in[7];
  const float* dt_proj  = (const float*)d_in[8];
  const float* dt_bias  = (const float*)d_in[9];
  const float* A_log    = (const float*)d_in[10];
  const float* D_param  = (const float*)d_in[11];
  const float* out_proj = (const float*)d_in[12];
  float* out = (float*)d_out;

  char* ws = (char*)d_ws;
  size_t off = 0;
  auto alloc = [&](size_t n) -> char* {
    char* p = ws + off;
    off = (off + n + 255) & ~(size_t)255;
    return p;
  };
  bf16_t* hb      = (bf16_t*)alloc((size_t)NTOK * DMODEL * 2);        // 8 MB
  bf16_t* w_in_b  = (bf16_t*)alloc((size_t)2*DINNER * DMODEL * 2);    // 8 MB
  bf16_t* w_out_b = (bf16_t*)alloc((size_t)DMODEL * DINNER * 2);      // 4 MB
  bf16_t* w_xp_b  = (bf16_t*)alloc((size_t)XPN * DINNER * 2);         // 0.4 MB
  bf16_t* w_dtp_b = (bf16_t*)alloc((size_t)DINNER * DTRANK * 2);      // 0.25 MB
  bf16_t* xzb     = (bf16_t*)alloc((size_t)NTOK * 2*DINNER * 2);      // 32 MB
  bf16_t* xconv   = (bf16_t*)alloc((size_t)NTOK * DINNER * 2);        // 16 MB
  float*  xdbl    = (float*) alloc((size_t)NTOK * XPN * 4);           // 1.5 MB
  bf16_t* dtlow   = (bf16_t*)alloc((size_t)NTOK * DTRANK * 2);        // 0.5 MB
  bf16_t* dtbuf   = (bf16_t*)alloc((size_t)NTOK * DINNER * 2);        // 16 MB
  float*  qbuf    = (float*) alloc((size_t)NBATCH*NCHUNK*DINNER*DSTATE*4); // 16 MB
  float*  sdbuf   = (float*) alloc((size_t)NBATCH*NCHUNK*DINNER*4);   // 1 MB
  bf16_t* ybuf    = (bf16_t*)alloc((size_t)NTOK * DINNER * 2);        // 16 MB
  (void)in_sizes; (void)n_in; (void)out_size; (void)ws_size;

  // zero the atomic accumulation target for x_proj
  hipMemsetAsync(xdbl, 0, (size_t)NTOK * XPN * sizeof(float), stream);

  // weight converts (inputs re-poisoned every call, so convert every call)
  cvt_bf16<<<4096, 256, 0, stream>>>(in_proj,  w_in_b,  (2*DINNER*DMODEL)/4);
  cvt_bf16<<<2048, 256, 0, stream>>>(out_proj, w_out_b, (DMODEL*DINNER)/4);
  cvt_bf16<<<192,  256, 0, stream>>>(x_proj,   w_xp_b,  (XPN*DINNER)/4);
  cvt_bf16<<<128,  256, 0, stream>>>(dt_proj,  w_dtp_b, (DINNER*DTRANK)/4);

  // 1. add + rmsnorm
  rmsnorm_kernel<<<NTOK, 256, 0, stream>>>(hidden, residual, norm_w, hb);
  // 2. xz = h * in_proj^T   (M=4096, N=4096, K=1024)
  gemm_bt_128<bf16_t><<<(NTOK/128)*(4*DINNER/128), 256, 0, stream>>>(
      hb, w_in_b, xzb, 2*DINNER, DMODEL, (2*DINNER)/128);
  // 3. causal depthwise conv + silu
  conv_silu<<<(NTOK*DINNER)/256, 256, 0, stream>>>(xzb, conv_w, conv_b, xconv);
  // 4. x_dbl = x * x_proj^T  (split-K, atomic)
  gemm_xproj<<<(NTOK/128)*8, 256, 0, stream>>>(xconv, w_xp_b, xdbl);
  // 5. dt_low -> bf16
  cvt_dtlow<<<(NTOK*DTRANK/4)/256, 256, 0, stream>>>(xdbl, dtlow);
  // 6. dt = softplus(dt_low * dt_proj^T + b)
  gemm_dtproj<<<(NTOK/128)*(DINNER/128), 256, 0, stream>>>(dtlow, w_dtp_b, dt_bias, dtbuf);
  // 7. chunked selective scan
  scan_passA<<<NBATCH*NCHUNK*(DINNER/256), 256, 0, stream>>>(dtbuf, xconv, xdbl, A_log, qbuf, sdbuf);
  scan_passB<<<(NBATCH*DINNER*DSTATE)/256, 256, 0, stream>>>(A_log, sdbuf, qbuf);
  scan_passC<<<NBATCH*NCHUNK*(DINNER/256), 256, 0, stream>>>(dtbuf, xconv, xzb, xdbl, A_log, D_param, qbuf, ybuf);
  // 8. out = y * out_proj^T  (M=4096, N=1024, K=2048)
  gemm_bt_128<float><<<(NTOK/128)*(DMODEL/128), 256, 0, stream>>>(
      ybuf, w_out_b, out, DMODEL, DINNER, DMODEL/128);
}